// Round 1
// baseline (165.185 us; speedup 1.0000x reference)
//
#include <hip/hip_runtime.h>
#include <stdint.h>

// VectorQuantizer on MI355X — round 8: barrier-free K-loop + 2x occupancy.
// Theory: R7 was latency-bound (MfmaUtil 10.5, VALU 13.5, HBM 18%, Occ 17%):
// (a) 32 stage->vmcnt(0)-drain barrier pairs in phase B (2-phase stall),
// (b) occupancy capped at 2x4-wave blocks/CU with 256 unified regs/wave.
// Fix: Ebf (512 KB bf16 codebook) is L2-resident -> read B-fragments
// DIRECTLY from global (common-mistake #7: don't LDS-stage L2-fit data).
// Zero barriers in the K-loop, 32 KB less LDS. Re-tile: 512-thread blocks
// (8 waves), wave tile 64 pos x 64 codes, acc[4][4]=64 regs -> <=128 VGPR
// -> 16 waves/CU (50% cap) via __launch_bounds__(512,4).
// Score math bit-identical to R7 (same bf16rne, same MFMA chain order over
// ch=0..7, same fadd(e2,-2*dot), same first-min {fkey|k} packing).
// latent [32,256,1024] fp32, codebook [1024,256] fp32.
// ws = [ Ebf bf16 chunk-planar [dq32][code1024][8] (512 KB) | e2 f32[1024] ].

#define D_   256
#define HW_  1024
#define N_   32768
#define K_   1024

typedef __attribute__((ext_vector_type(8))) short  s8v;   // 8 bf16 (4 VGPR)
typedef __attribute__((ext_vector_type(4))) float  f4v;   // MFMA acc

__device__ __forceinline__ ushort bf16rne(float x) {
  unsigned u = __float_as_uint(x);
  return (ushort)((u + 0x7FFFu + ((u >> 16) & 1u)) >> 16);
}

// monotone map: unsigned order of key == float order (handles negatives)
__device__ __forceinline__ unsigned fkey(float f) {
  unsigned u = __float_as_uint(f);
  return u ^ (unsigned)(((int)u >> 31) | 0x80000000);
}

// ---------- codebook -> bf16 chunk-planar Ebf + numpy-pairwise e2 + loss=0 ----------
// (unchanged from R7 — outputs must stay bit-identical)
__global__ __launch_bounds__(256) void k_eprep(const float* __restrict__ cb,
                                               ushort* __restrict__ Ebf,
                                               float* __restrict__ e2,
                                               float* __restrict__ loss) {
  const int t = threadIdx.x, blk = blockIdx.x;   // 64 blocks x 16 codes
  if (blk == 0 && t == 0) *loss = 0.f;
#pragma unroll
  for (int it = 0; it < 2; ++it) {
    int c = it * 256 + t;                        // 512 chunks/block
    int cl = c & 15, dq = c >> 4;                // code-local, d-chunk
    const float* src = cb + (size_t)(blk * 16 + cl) * 256 + dq * 8;
    float4 v0 = ((const float4*)src)[0], v1 = ((const float4*)src)[1];
    ushort tmp[8] __attribute__((aligned(16)));
    tmp[0] = bf16rne(v0.x); tmp[1] = bf16rne(v0.y);
    tmp[2] = bf16rne(v0.z); tmp[3] = bf16rne(v0.w);
    tmp[4] = bf16rne(v1.x); tmp[5] = bf16rne(v1.y);
    tmp[6] = bf16rne(v1.z); tmp[7] = bf16rne(v1.w);
    *(uint4*)(Ebf + ((size_t)dq * 1024 + blk * 16 + cl) * 8) = *(uint4*)tmp;
  }
  // e2 numpy-pairwise: 16 lanes/row, butterfly reproduces pairwise tree
  const int row = blk * 16 + (t >> 4);
  const int sub = t & 15, j = sub & 7, h = sub >> 3;
  const float* base = cb + row * 256 + h * 128 + j;
  float r = __fmul_rn(base[0], base[0]);
  for (int i = 1; i < 16; ++i) {
    float v = base[8 * i];
    r = __fadd_rn(r, __fmul_rn(v, v));
  }
#pragma unroll
  for (int m = 1; m < 16; m <<= 1) r = __fadd_rn(r, __shfl_xor(r, m, 64));
  if (sub == 0) e2[row] = r;
}

// ---------- fused: convert + MFMA-argmin over K=1024 + gather + out + loss ----------
// Grid 512 tiles (64 pos, hw-contiguous). Block 512 = 8 waves.
// LDS: Xbf 32 KB persistent A-operand [dq(32)][pos(64)][8] + e2s 4 KB +
// bests 512 B  (~37 KB -> 2 blocks/CU; reg cap 128 -> 4 waves/SIMD).
// Wave tile 64 pos x 64 codes = acc[4][4]. B-fragments come straight from
// global Ebf (L2-hit, coalesced 256 B per 16 lanes) — NO barriers in K-loop.
__global__ __launch_bounds__(512, 4) void k_fused(
    const float* __restrict__ latent, const float* __restrict__ cb,
    const ushort* __restrict__ Ebf, const float* __restrict__ e2g,
    float* __restrict__ out, float* __restrict__ loss) {
  __shared__ alignas(16) ushort Xbf[32 * 64 * 8];   // 32 KB
  __shared__ alignas(16) float e2s[1024];           // 4 KB
  __shared__ unsigned long long bests[64];
  __shared__ float red[8];

  const int t = threadIdx.x, tile = blockIdx.x;     // 512 tiles x 64 pos
  const int b = tile >> 4, hw0 = (tile & 15) * 64;
  const int lane = t & 63, w = t >> 6;              // wave 0..7
  const int lrow = lane & 15, q = lane >> 4;

  ((float2*)e2s)[t] = ((const float2*)e2g)[t];      // 1024 floats, 512 thr
  if (t < 64) bests[t] = ~0ull;

  // ---- Phase A: latent tile -> Xbf (bf16, chunk-planar), register transpose ----
  // thread t: dq = t>>4 (d-chunk of 8), pg = t&15 (pos-group of 4)
  const float* Lb = latent + (size_t)b * (D_ * HW_) + hw0;
  {
    const int dq = t >> 4, pg = t & 15;
    float4 v[8];
#pragma unroll
    for (int e = 0; e < 8; ++e)                      // coalesced: 16 lanes x 16 B
      v[e] = *(const float4*)(Lb + (size_t)(dq * 8 + e) * HW_ + pg * 4);
#pragma unroll
    for (int r = 0; r < 4; ++r) {
      ushort tmp[8] __attribute__((aligned(16)));
#pragma unroll
      for (int e = 0; e < 8; ++e) {
        float fv = (r == 0) ? v[e].x : (r == 1) ? v[e].y : (r == 2) ? v[e].z
                                                                    : v[e].w;
        tmp[e] = bf16rne(fv);
      }
      *(uint4*)&Xbf[((size_t)dq * 64 + pg * 4 + r) * 8] = *(uint4*)tmp;
    }
  }
  __syncthreads();                                   // Xbf + e2s + bests ready

  // ---- Phase B: K-loop over 1024 codes, argmin (NO barriers inside) ----
  // lane (q,lrow) of wave w: A row = pos mi*16+lrow, d-slice q of chunk ch;
  // B col = code kh + w*64 + kj*16 + lrow, same d-slice. B read from global.
  const ushort* Bb = Ebf + ((size_t)q * 1024 + w * 64 + lrow) * 8;

#pragma unroll 1
  for (int ms = 0; ms < 2; ++ms) {                   // 2 halves of 512 codes
    const int kh = ms * 512;
    const ushort* Bh = Bb + (size_t)kh * 8;
    f4v acc[4][4];
#pragma unroll
    for (int mi = 0; mi < 4; ++mi)
#pragma unroll
      for (int kj = 0; kj < 4; ++kj) acc[mi][kj] = (f4v){0.f, 0.f, 0.f, 0.f};

    for (int ch = 0; ch < 8; ++ch) {                 // chunks of 32 d
      s8v a_[4];
#pragma unroll
      for (int mi = 0; mi < 4; ++mi)
        a_[mi] = *(const s8v*)&Xbf[((size_t)(ch * 4 + q) * 64 + mi * 16 + lrow) * 8];
      s8v b4[4];
#pragma unroll
      for (int kj = 0; kj < 4; ++kj)                 // L2-hit global_load_dwordx4
        b4[kj] = *(const s8v*)(Bh + (size_t)ch * 32768 + kj * 128);
#pragma unroll
      for (int kj = 0; kj < 4; ++kj)
#pragma unroll
        for (int mi = 0; mi < 4; ++mi)
          acc[mi][kj] = __builtin_amdgcn_mfma_f32_16x16x32_bf16(
              a_[mi], b4[kj], acc[mi][kj], 0, 0, 0);
    }

    // per-half epilogue: per-lane first-min over kj, then 16-lane butterfly,
    // then cross-wave/cross-half merge via atomicMin on {fkey|k}.
    float best[4][4];
    int bestk[4][4];
#pragma unroll
    for (int mi = 0; mi < 4; ++mi)
#pragma unroll
      for (int reg = 0; reg < 4; ++reg) { best[mi][reg] = 3.4e38f; bestk[mi][reg] = 0; }
#pragma unroll
    for (int kj = 0; kj < 4; ++kj) {                 // kj ascending: first-min
      int code = kh + w * 64 + kj * 16 + lrow;
      float e2v = e2s[code];
#pragma unroll
      for (int mi = 0; mi < 4; ++mi)
#pragma unroll
        for (int reg = 0; reg < 4; ++reg) {
          float s = __fadd_rn(e2v, -2.f * acc[mi][kj][reg]);
          if (s < best[mi][reg]) { best[mi][reg] = s; bestk[mi][reg] = code; }
        }
    }
#pragma unroll
    for (int mi = 0; mi < 4; ++mi)
#pragma unroll
      for (int reg = 0; reg < 4; ++reg) {
        float bv = best[mi][reg];
        int bk = bestk[mi][reg];
#pragma unroll
        for (int m = 1; m < 16; m <<= 1) {
          float ob = __shfl_xor(bv, m, 64);
          int ok = __shfl_xor(bk, m, 64);
          if (ob < bv || (ob == bv && ok < bk)) { bv = ob; bk = ok; }
        }
        if (lrow == 0) {
          int pos = mi * 16 + q * 4 + reg;
          atomicMin(&bests[pos],
                    ((unsigned long long)fkey(bv) << 32) | (unsigned)bk);
        }
      }
  }
  __syncthreads();                                   // bests final

  // ---- Phase C: gather + straight-through output + loss ----
  const int posq = t & 15;                           // pos-group of 4
  const int drow = t >> 4;                           // 0..31 d-slice
  int kk[4];
#pragma unroll
  for (int e = 0; e < 4; ++e)
    kk[e] = (int)(unsigned)(bests[posq * 4 + e] & 0xFFFFFFFFull);
  float* Ob = out + (size_t)b * (D_ * HW_) + hw0 + posq * 4;
  const float* Lb2 = Lb + posq * 4;
  float part = 0.f;
#pragma unroll 2
  for (int it = 0; it < 8; ++it) {
    int d = it * 32 + drow;
    float4 x = *(const float4*)(Lb2 + (size_t)d * HW_);
    float4 o;
    float qv, df;
    qv = cb[(size_t)kk[0] * 256 + d]; df = __fsub_rn(qv, x.x); o.x = __fadd_rn(x.x, df); part = fmaf(df, df, part);
    qv = cb[(size_t)kk[1] * 256 + d]; df = __fsub_rn(qv, x.y); o.y = __fadd_rn(x.y, df); part = fmaf(df, df, part);
    qv = cb[(size_t)kk[2] * 256 + d]; df = __fsub_rn(qv, x.z); o.z = __fadd_rn(x.z, df); part = fmaf(df, df, part);
    qv = cb[(size_t)kk[3] * 256 + d]; df = __fsub_rn(qv, x.w); o.w = __fadd_rn(x.w, df); part = fmaf(df, df, part);
    *(float4*)(Ob + (size_t)d * HW_) = o;            // x + (q - x), NOT q
  }
#pragma unroll
  for (int off = 32; off > 0; off >>= 1) part += __shfl_down(part, off, 64);
  if (lane == 0) red[w] = part;
  __syncthreads();
  if (t == 0) {
    float tot = 0.f;
#pragma unroll
    for (int i = 0; i < 8; ++i) tot += red[i];
    atomicAdd(loss, tot * (1.25f / 8388608.0f));
  }
}

extern "C" void kernel_launch(void* const* d_in, const int* in_sizes, int n_in,
                              void* d_out, int out_size, void* d_ws, size_t ws_size,
                              hipStream_t stream) {
  const float* latent = (const float*)d_in[0];
  const float* cb     = (const float*)d_in[1];
  float* out  = (float*)d_out;
  float* loss = out + (size_t)N_ * D_;             // element 8,388,608
  ushort* Ebf = (ushort*)d_ws;                     // 512 KB chunk-planar bf16
  float*  e2  = (float*)((char*)d_ws + (size_t)K_ * D_ * sizeof(ushort));

  hipLaunchKernelGGL(k_eprep, dim3(64),  dim3(256), 0, stream, cb, Ebf, e2, loss);
  hipLaunchKernelGGL(k_fused, dim3(512), dim3(512), 0, stream,
                     latent, cb, Ebf, e2, out, loss);
}